// Round 10
// baseline (200.953 us; speedup 1.0000x reference)
//
#include <hip/hip_runtime.h>
#include <hip/hip_cooperative_groups.h>
#include <math.h>

namespace cg = cooperative_groups;

// Problem constants (match reference)
#define BB 8
#define NN 4096
#define LATENT 256

#define THREADS 256
#define NQ 16                         // queries per thread (4 float4 groups)
#define CSPLIT 32                     // candidate tiles
#define TT (NN / CSPLIT)              // 128 candidates per tile
#define NSLOTS (2 * BB * NN)          // 65536 query slots
#define NBLOCKS (2 * BB * CSPLIT)    // 512 blocks (2 per CU -> co-resident)

// Order-preserving float<->uint encoding (monotone; validated R4/R5)
__device__ __forceinline__ unsigned enc(float f) {
    unsigned b = __float_as_uint(f);
    return (b & 0x80000000u) ? ~b : (b | 0x80000000u);
}
__device__ __forceinline__ float dec(unsigned k) {
    unsigned b = (k & 0x80000000u) ? (k ^ 0x80000000u) : ~k;
    return __uint_as_float(b);
}

__device__ __forceinline__ float min3f(float a, float b, float c) {
    float d;
    asm("v_min3_f32 %0, %1, %2, %3" : "=v"(d) : "v"(a), "v"(b), "v"(c));
    return d;
}

// ---------------------------------------------------------------------------
// Single cooperative kernel:
//  P0: init minkeys (in-kernel -> replay-safe, no memset dispatch)
//  P1: scan: block (bx=bid&15 -> dir,b ; c=bid>>4): 128 candidates in LDS,
//      16 queries/thread, scalar v_fma_f32 + v_min3_f32 (3.5 instr/pair),
//      per-slot enc-atomicMin (2M atomics, order-independent).
//  P2: 256 blocks sum 256 decoded keys each -> sums[bid]  (256 KB total)
//  P3: block 0: sum 256 totals + KL, write 3 outputs.
// ---------------------------------------------------------------------------
__global__ __launch_bounds__(THREADS)
void aether_fused(const float* __restrict__ recon,
                  const float* __restrict__ x,
                  const float* __restrict__ mu,
                  const float* __restrict__ logvar,
                  unsigned* __restrict__ minkeys,
                  float* __restrict__ sums,
                  float* __restrict__ out)
{
    cg::grid_group grid = cg::this_grid();

    __shared__ float4 ly[TT];        // 2 KB
    __shared__ float red[4];

    const int bid = blockIdx.x;      // 0..511
    const int tid = threadIdx.x;
    const int gid = bid * THREADS + tid;

    // ---- Phase 0: init ----
    if (gid < NSLOTS) minkeys[gid] = 0xFFFFFFFFu;
    grid.sync();

    // ---- Phase 1: scan ----
    {
        const int bx  = bid & 15;        // dir*8 + b
        const int c   = bid >> 4;        // 0..31
        const int dir = bx >> 3;
        const int b   = bx & 7;

        const float* cloud = (dir ? recon : x) + (size_t)b * 3 * NN;
        const float* query = (dir ? x : recon) + (size_t)b * 3 * NN;

        for (int i = tid; i < TT; i += THREADS) {
            int m = c * TT + i;
            float y0 = cloud[m];
            float y1 = cloud[NN + m];
            float y2 = cloud[2 * NN + m];
            ly[i] = make_float4(-2.0f * y0, -2.0f * y1, -2.0f * y2,
                                y0 * y0 + y1 * y1 + y2 * y2);
        }
        __syncthreads();

        // 16 queries/thread: group g covers queries g*1024 + tid*4 + {0..3}
        const float4* q4x = (const float4*)(query);
        const float4* q4y = (const float4*)(query + NN);
        const float4* q4z = (const float4*)(query + 2 * NN);

        float qx[NQ], qy[NQ], qz[NQ], mn[NQ];
#pragma unroll
        for (int g = 0; g < 4; ++g) {
            float4 vx = q4x[g * 256 + tid];
            float4 vy = q4y[g * 256 + tid];
            float4 vz = q4z[g * 256 + tid];
            qx[4*g+0] = vx.x; qx[4*g+1] = vx.y; qx[4*g+2] = vx.z; qx[4*g+3] = vx.w;
            qy[4*g+0] = vy.x; qy[4*g+1] = vy.y; qy[4*g+2] = vy.z; qy[4*g+3] = vy.w;
            qz[4*g+0] = vz.x; qz[4*g+1] = vz.y; qz[4*g+2] = vz.z; qz[4*g+3] = vz.w;
        }
#pragma unroll
        for (int k = 0; k < NQ; ++k) mn[k] = 3.4e38f;

#pragma unroll 2
        for (int j = 0; j < TT; j += 2) {
            float4 A = ly[j];            // broadcast ds_read_b128, serves 16 pairs
            float4 B = ly[j + 1];
#pragma unroll
            for (int k = 0; k < NQ; ++k) {
                float tA = fmaf(qx[k], A.x, fmaf(qy[k], A.y, fmaf(qz[k], A.z, A.w)));
                float tB = fmaf(qx[k], B.x, fmaf(qy[k], B.y, fmaf(qz[k], B.z, B.w)));
                mn[k] = min3f(mn[k], tA, tB);
            }
        }

        const int base = dir * (BB * NN) + b * NN;
#pragma unroll
        for (int g = 0; g < 4; ++g) {
#pragma unroll
            for (int e = 0; e < 4; ++e) {
                int k = 4 * g + e;
                float sx = fmaf(qx[k], qx[k], fmaf(qy[k], qy[k], qz[k] * qz[k]));
                int q = g * 1024 + tid * 4 + e;
                atomicMin(&minkeys[base + q], enc(sx + mn[k]));
            }
        }
    }
    grid.sync();

    // ---- Phase 2: partial sums (blocks 0..255) ----
    if (bid < NSLOTS / THREADS) {
        float v = dec(minkeys[bid * THREADS + tid]);
        for (int off = 32; off > 0; off >>= 1)
            v += __shfl_down(v, off);
        if ((tid & 63) == 0) red[tid >> 6] = v;
        __syncthreads();
        if (tid == 0)
            sums[bid] = red[0] + red[1] + red[2] + red[3];
    }
    grid.sync();

    // ---- Phase 3: finalize (block 0) ----
    if (bid == 0) {
        __shared__ float redA[4];
        __shared__ float redB[4];

        float s = sums[tid];   // exactly 256 partials

        float kl = 0.0f;
        for (int i = tid; i < BB * LATENT; i += THREADS) {
            float m  = mu[i];
            float lv = logvar[i];
            kl += 1.0f + lv - m * m - expf(lv);
        }

        for (int off = 32; off > 0; off >>= 1) {
            s  += __shfl_down(s, off);
            kl += __shfl_down(kl, off);
        }
        if ((tid & 63) == 0) { redA[tid >> 6] = s; redB[tid >> 6] = kl; }
        __syncthreads();
        if (tid == 0) {
            float recon_l = (redA[0] + redA[1] + redA[2] + redA[3]) / (float)(BB * NN);
            float kld     = -0.5f * (redB[0] + redB[1] + redB[2] + redB[3]) / (float)BB;
            out[0] = recon_l + kld;   // BETA = 1
            out[1] = recon_l;
            out[2] = kld;
        }
    }
}

extern "C" void kernel_launch(void* const* d_in, const int* in_sizes, int n_in,
                              void* d_out, int out_size, void* d_ws, size_t ws_size,
                              hipStream_t stream)
{
    const float* recon  = (const float*)d_in[0];
    const float* x      = (const float*)d_in[1];
    const float* mu     = (const float*)d_in[2];
    const float* logvar = (const float*)d_in[3];
    float* out = (float*)d_out;

    unsigned* minkeys = (unsigned*)d_ws;             // 65536 uints (256 KB)
    float*    sums    = (float*)(minkeys + NSLOTS);  // 256 floats

    void* args[] = { (void*)&recon, (void*)&x, (void*)&mu, (void*)&logvar,
                     (void*)&minkeys, (void*)&sums, (void*)&out };
    hipLaunchCooperativeKernel((const void*)aether_fused,
                               dim3(NBLOCKS), dim3(THREADS),
                               args, 0, stream);
}